// Round 8
// baseline (942.429 us; speedup 1.0000x reference)
//
#include <hip/hip_runtime.h>
#include <hip/hip_fp16.h>
#include <hip/hip_cooperative_groups.h>

namespace cg = cooperative_groups;

// Problem constants (from reference setup_inputs)
constexpr int Bsz   = 1024;     // batch
constexpr int F0    = 20000;    // input features
constexpr int NOUT0 = 5000, NOUT1 = 1000, NOUT2 = 256;
constexpr int NE0   = 100000, NE1 = 50000, NE2 = 10000;
constexpr int CNT_N  = NOUT0 + NOUT1 + NOUT2;   // 6256
constexpr int OFFS_N = CNT_N + 3;               // 6259
constexpr int CSR_N  = NE0 + NE1 + NE2;         // 160000
constexpr int MAXIDX = 512;
constexpr int NTILE_F = (F0 + 63) / 64;         // 313
constexpr int NTILE   = NTILE_F * (Bsz / 64);   // 5008 transpose tiles

union H4 { uint2 u; __half2 h[2]; };

struct Params {
    const float* data; const float* p0; const float* p1; const float* p2;
    const float* W; const float* bias;
    const int* src0; const int* dst0; const int* src1; const int* dst1;
    const int* src2; const int* dst2;
    __half* dataT; __half* y0; __half* y1; __half* y2;
    int* cnt; int* offs; int* cursor; int* csr;
    float* out;
};

// ---------------------------------------------------------------------------
// Layer phase (device fn): grid-stride over dst buckets; fp16 I/O, fp32 acc.
__device__ __forceinline__ void layer_phase(
    const __half* __restrict__ xT, const int* __restrict__ csr,
    const int* __restrict__ offs, const float* __restrict__ pnext,
    __half* __restrict__ yT, int nout, int* sidx)
{
    const int t = threadIdx.x;
    for (int j = blockIdx.x; j < nout; j += gridDim.x) {
        const int beg = offs[j], end = offs[j + 1];
        const int n = end - beg;
        const int np = n < MAXIDX ? n : MAXIDX;
        __syncthreads();                      // protect sidx from prev iter readers
        for (int i = t; i < np; i += 256) sidx[i] = csr[beg + i];
        __syncthreads();

        const int c = t * 4;
        float4 a0 = make_float4(0.f, 0.f, 0.f, 0.f);
        float4 a1 = make_float4(0.f, 0.f, 0.f, 0.f);
        int e = 0;
        for (; e + 2 <= np; e += 2) {
            H4 u0, u1;
            u0.u = *(const uint2*)&xT[(size_t)sidx[e + 0] * Bsz + c];
            u1.u = *(const uint2*)&xT[(size_t)sidx[e + 1] * Bsz + c];
            const float2 f00 = __half22float2(u0.h[0]);
            const float2 f01 = __half22float2(u0.h[1]);
            const float2 f10 = __half22float2(u1.h[0]);
            const float2 f11 = __half22float2(u1.h[1]);
            a0.x += f00.x; a0.y += f00.y; a0.z += f01.x; a0.w += f01.y;
            a1.x += f10.x; a1.y += f10.y; a1.z += f11.x; a1.w += f11.y;
        }
        if (e < np) {
            H4 u; u.u = *(const uint2*)&xT[(size_t)sidx[e] * Bsz + c];
            const float2 f0 = __half22float2(u.h[0]);
            const float2 f1 = __half22float2(u.h[1]);
            a0.x += f0.x; a0.y += f0.y; a0.z += f1.x; a0.w += f1.y;
        }
        for (int ee = MAXIDX; ee < n; ++ee) {   // overflow fallback (never in practice)
            H4 u; u.u = *(const uint2*)&xT[(size_t)csr[beg + ee] * Bsz + c];
            const float2 f0 = __half22float2(u.h[0]);
            const float2 f1 = __half22float2(u.h[1]);
            a0.x += f0.x; a0.y += f0.y; a0.z += f1.x; a0.w += f1.y;
        }
        a0.x += a1.x; a0.y += a1.y; a0.z += a1.z; a0.w += a1.w;

        const float inv = 1.0f / fmaxf((float)n, 1.0f);
        const float sc = (pnext ? pnext[j] : 1.0f) * inv;
        H4 o;
        o.h[0] = __floats2half2_rn(fmaxf(a0.x, 0.f) * sc, fmaxf(a0.y, 0.f) * sc);
        o.h[1] = __floats2half2_rn(fmaxf(a0.z, 0.f) * sc, fmaxf(a0.w, 0.f) * sc);
        *(uint2*)&yT[(size_t)j * Bsz + c] = o.u;
    }
}

// ---------------------------------------------------------------------------
// The whole network as ONE cooperative kernel.
__global__ __launch_bounds__(256, 4) void gnn_all(Params P)
{
    __shared__ __align__(16) char shraw[64 * 65 * 4];   // 16640 B, phase-shared
    float (*tile)[65] = reinterpret_cast<float (*)[65]>(shraw);
    int* ishare = reinterpret_cast<int*>(shraw);

    cg::grid_group grd = cg::this_grid();
    const int t   = threadIdx.x;
    const int bid = blockIdx.x;
    const int nb  = gridDim.x;

    // P0: zero cnt
    for (int i = bid * 256 + t; i < CNT_N; i += nb * 256) P.cnt[i] = 0;
    grd.sync();

    // P1: count dst in-degrees
    for (int i = bid * 256 + t; i < CSR_N; i += nb * 256) {
        if (i < NE0)            atomicAdd(&P.cnt[P.dst0[i]], 1);
        else if (i < NE0 + NE1) atomicAdd(&P.cnt[NOUT0 + P.dst1[i - NE0]], 1);
        else                    atomicAdd(&P.cnt[NOUT0 + NOUT1 + P.dst2[i - NE0 - NE1]], 1);
    }
    grd.sync();

    // P2: scan (blocks 0..2)  ||  transpose+scale fp32->fp16 (blocks 3..)
    if (bid < 3) {
        const int L  = bid;
        const int n  = (L == 0) ? NOUT0 : (L == 1) ? NOUT1 : NOUT2;
        const int cb = (L == 0) ? 0 : (L == 1) ? NOUT0 : NOUT0 + NOUT1;
        const int ob = (L == 0) ? 0 : (L == 1) ? NOUT0 + 1 : NOUT0 + NOUT1 + 2;
        const int* c = P.cnt + cb;
        int* ofs = P.offs + ob;
        int* cur = P.cursor + cb;
        int vals[20];
        int local = 0;
        const int base = t * 20;               // 256*20 = 5120 >= 5000
#pragma unroll
        for (int k = 0; k < 20; ++k) {
            const int i = base + k;
            const int v = (i < n) ? c[i] : 0;
            vals[k] = v; local += v;
        }
        ishare[t] = local;
        __syncthreads();
        for (int d = 1; d < 256; d <<= 1) {
            const int v = (t >= d) ? ishare[t - d] : 0;
            __syncthreads();
            ishare[t] += v;
            __syncthreads();
        }
        int excl = ishare[t] - local;
#pragma unroll
        for (int k = 0; k < 20; ++k) {
            const int i = base + k;
            if (i < n) { ofs[i] = excl; cur[i] = excl; }
            excl += vals[k];
        }
        if (t == 255) ofs[n] = ishare[255];
    } else {
        for (int tj = bid - 3; tj < NTILE; tj += nb - 3) {
            const int c0 = (tj % NTILE_F) * 64;   // F0 dim
            const int r0 = (tj / NTILE_F) * 64;   // B dim
            __syncthreads();                       // tile reuse guard
            const int f4 = t & 15, rr = t >> 4;
            const int col = c0 + f4 * 4;
            if (col < F0) {                        // F0 % 4 == 0: exact guard
#pragma unroll
                for (int p = 0; p < 4; ++p) {
                    const int br = rr + p * 16;
                    const float4 v = *(const float4*)&P.data[(size_t)(r0 + br) * F0 + col];
                    tile[br][f4 * 4 + 0] = v.x;
                    tile[br][f4 * 4 + 1] = v.y;
                    tile[br][f4 * 4 + 2] = v.z;
                    tile[br][f4 * 4 + 3] = v.w;
                }
            }
            __syncthreads();
            const int b4 = t & 15, fr = t >> 4;
#pragma unroll
            for (int p = 0; p < 4; ++p) {
                const int f = c0 + fr + p * 16;
                if (f < F0) {
                    const float s = P.p0[f];
                    H4 o;
                    o.h[0] = __floats2half2_rn(tile[b4 * 4 + 0][fr + p * 16] * s,
                                               tile[b4 * 4 + 1][fr + p * 16] * s);
                    o.h[1] = __floats2half2_rn(tile[b4 * 4 + 2][fr + p * 16] * s,
                                               tile[b4 * 4 + 3][fr + p * 16] * s);
                    *(uint2*)&P.dataT[(size_t)f * Bsz + r0 + b4 * 4] = o.u;
                }
            }
        }
    }
    grd.sync();

    // P3: scatter edges into CSR
    for (int i = bid * 256 + t; i < CSR_N; i += nb * 256) {
        if (i < NE0) {
            const int pos = atomicAdd(&P.cursor[P.dst0[i]], 1);
            P.csr[pos] = P.src0[i];
        } else if (i < NE0 + NE1) {
            const int k = i - NE0;
            const int pos = atomicAdd(&P.cursor[NOUT0 + P.dst1[k]], 1);
            P.csr[NE0 + pos] = P.src1[k];
        } else {
            const int k = i - NE0 - NE1;
            const int pos = atomicAdd(&P.cursor[NOUT0 + NOUT1 + P.dst2[k]], 1);
            P.csr[NE0 + NE1 + pos] = P.src2[k];
        }
    }
    grd.sync();

    // P4..P6: the three gather layers
    layer_phase(P.dataT, P.csr, P.offs, P.p1, P.y0, NOUT0, ishare);
    grd.sync();
    layer_phase(P.y0, P.csr + NE0, P.offs + NOUT0 + 1, P.p2, P.y1, NOUT1, ishare);
    grd.sync();
    layer_phase(P.y1, P.csr + NE0 + NE1, P.offs + NOUT0 + NOUT1 + 2, nullptr, P.y2, NOUT2, ishare);
    grd.sync();

    // P7: head (blocks 0..3): out (B,10) = y2 @ W.T + b
    if (bid < Bsz / 256) {
        float* wsh = reinterpret_cast<float*>(shraw);
        float* bsh = wsh + 2560;
        for (int i = t; i < 2560; i += 256) wsh[i] = P.W[i];
        if (t < 10) bsh[t] = P.bias[t];
        __syncthreads();
        const int b = bid * 256 + t;
        float acc[10];
#pragma unroll
        for (int o = 0; o < 10; ++o) acc[o] = bsh[o];
        for (int k = 0; k < 256; ++k) {
            const float v = __half2float(P.y2[(size_t)k * Bsz + b]);
#pragma unroll
            for (int o = 0; o < 10; ++o) acc[o] += v * wsh[o * 256 + k];
        }
#pragma unroll
        for (int o = 0; o < 10; ++o) P.out[(size_t)b * 10 + o] = acc[o];
    }
}

// ===========================================================================
// Fallback path: proven round-7 split kernels (used only if coop launch fails).
// ===========================================================================
__global__ __launch_bounds__(256) void transpose_scale(
    const float* __restrict__ data, const float* __restrict__ p0,
    __half* __restrict__ dataT)
{
    __shared__ float tile[64][65];
    const int t  = threadIdx.x;
    const int c0 = blockIdx.x * 64;
    const int r0 = blockIdx.y * 64;
    const int f4 = t & 15, rr = t >> 4;
    const int col = c0 + f4 * 4;
    if (col < F0) {
#pragma unroll
        for (int p = 0; p < 4; ++p) {
            const int br = rr + p * 16;
            const float4 v = *(const float4*)&data[(size_t)(r0 + br) * F0 + col];
            tile[br][f4 * 4 + 0] = v.x; tile[br][f4 * 4 + 1] = v.y;
            tile[br][f4 * 4 + 2] = v.z; tile[br][f4 * 4 + 3] = v.w;
        }
    }
    __syncthreads();
    const int b4 = t & 15, fr = t >> 4;
#pragma unroll
    for (int p = 0; p < 4; ++p) {
        const int f = c0 + fr + p * 16;
        if (f < F0) {
            const float s = p0[f];
            H4 o;
            o.h[0] = __floats2half2_rn(tile[b4 * 4 + 0][fr + p * 16] * s,
                                       tile[b4 * 4 + 1][fr + p * 16] * s);
            o.h[1] = __floats2half2_rn(tile[b4 * 4 + 2][fr + p * 16] * s,
                                       tile[b4 * 4 + 3][fr + p * 16] * s);
            *(uint2*)&dataT[(size_t)f * Bsz + r0 + b4 * 4] = o.u;
        }
    }
}

__global__ __launch_bounds__(256) void count_edges(
    const int* __restrict__ dst0, const int* __restrict__ dst1,
    const int* __restrict__ dst2, int* __restrict__ cnt)
{
    const int i = blockIdx.x * 256 + threadIdx.x;
    if (i < NE0)                 atomicAdd(&cnt[dst0[i]], 1);
    else if (i < NE0 + NE1)      atomicAdd(&cnt[NOUT0 + dst1[i - NE0]], 1);
    else if (i < CSR_N)          atomicAdd(&cnt[NOUT0 + NOUT1 + dst2[i - NE0 - NE1]], 1);
}

__global__ __launch_bounds__(1024) void scan_offs(
    const int* __restrict__ cnt, int* __restrict__ offs, int* __restrict__ cursor)
{
    const int L = blockIdx.x;
    const int nout  = (L == 0) ? NOUT0 : (L == 1) ? NOUT1 : NOUT2;
    const int cbase = (L == 0) ? 0 : (L == 1) ? NOUT0 : NOUT0 + NOUT1;
    const int obase = (L == 0) ? 0 : (L == 1) ? NOUT0 + 1 : NOUT0 + NOUT1 + 2;
    const int* c  = cnt + cbase;
    int* ofs      = offs + obase;
    int* cur      = cursor + cbase;
    __shared__ int lds[1024];
    const int t = threadIdx.x;
    constexpr int CHUNK = 5;
    const int base = t * CHUNK;
    int vals[CHUNK];
    int local = 0;
#pragma unroll
    for (int k = 0; k < CHUNK; ++k) {
        const int i = base + k;
        const int v = (i < nout) ? c[i] : 0;
        vals[k] = v; local += v;
    }
    lds[t] = local;
    __syncthreads();
    for (int d = 1; d < 1024; d <<= 1) {
        const int v = (t >= d) ? lds[t - d] : 0;
        __syncthreads();
        lds[t] += v;
        __syncthreads();
    }
    int excl = lds[t] - local;
#pragma unroll
    for (int k = 0; k < CHUNK; ++k) {
        const int i = base + k;
        if (i < nout) { ofs[i] = excl; cur[i] = excl; }
        excl += vals[k];
    }
    if (t == 1023) ofs[nout] = lds[1023];
}

__global__ __launch_bounds__(256) void scatter_edges(
    const int* __restrict__ src0, const int* __restrict__ dst0,
    const int* __restrict__ src1, const int* __restrict__ dst1,
    const int* __restrict__ src2, const int* __restrict__ dst2,
    int* __restrict__ cursor, int* __restrict__ csr)
{
    const int i = blockIdx.x * 256 + threadIdx.x;
    if (i < NE0) {
        const int pos = atomicAdd(&cursor[dst0[i]], 1);
        csr[pos] = src0[i];
    } else if (i < NE0 + NE1) {
        const int k = i - NE0;
        const int pos = atomicAdd(&cursor[NOUT0 + dst1[k]], 1);
        csr[NE0 + pos] = src1[k];
    } else if (i < CSR_N) {
        const int k = i - NE0 - NE1;
        const int pos = atomicAdd(&cursor[NOUT0 + NOUT1 + dst2[k]], 1);
        csr[NE0 + NE1 + pos] = src2[k];
    }
}

__global__ __launch_bounds__(256) void layer_fwd(
    const __half* __restrict__ xT, const int* __restrict__ csr,
    const int* __restrict__ offs, const float* __restrict__ pnext,
    __half* __restrict__ yT)
{
    __shared__ int sidx[MAXIDX];
    layer_phase(xT, csr, offs, pnext, yT, gridDim.x, sidx);  // grid == nout exactly
}

__global__ __launch_bounds__(256) void head_gemm(
    const __half* __restrict__ y2T, const float* __restrict__ W,
    const float* __restrict__ bias, float* __restrict__ out)
{
    __shared__ float ws[10 * 256];
    __shared__ float bs[10];
    const int t = threadIdx.x;
    for (int i = t; i < 10 * 256; i += 256) ws[i] = W[i];
    if (t < 10) bs[t] = bias[t];
    __syncthreads();
    const int b = blockIdx.x * 256 + t;
    float acc[10];
#pragma unroll
    for (int o = 0; o < 10; ++o) acc[o] = bs[o];
    for (int k = 0; k < 256; ++k) {
        const float v = __half2float(y2T[(size_t)k * Bsz + b]);
#pragma unroll
        for (int o = 0; o < 10; ++o) acc[o] += v * ws[o * 256 + k];
    }
#pragma unroll
    for (int o = 0; o < 10; ++o) out[(size_t)b * 10 + o] = acc[o];
}

// ---------------------------------------------------------------------------
extern "C" void kernel_launch(void* const* d_in, const int* in_sizes, int n_in,
                              void* d_out, int out_size, void* d_ws, size_t ws_size,
                              hipStream_t stream)
{
    const float* data = (const float*)d_in[0];
    const float* p0   = (const float*)d_in[1];
    const float* p1   = (const float*)d_in[2];
    const float* p2   = (const float*)d_in[3];
    const float* W    = (const float*)d_in[4];
    const float* bias = (const float*)d_in[5];
    const int* src0 = (const int*)d_in[6];
    const int* dst0 = (const int*)d_in[7];
    const int* src1 = (const int*)d_in[8];
    const int* dst1 = (const int*)d_in[9];
    const int* src2 = (const int*)d_in[10];
    const int* dst2 = (const int*)d_in[11];

    char* ws = (char*)d_ws;
    auto align = [](size_t x) { return (x + 255) & ~size_t(255); };
    size_t o = 0;
    __half* dataT = (__half*)(ws + o); o = align(o + (size_t)F0 * Bsz * 2);
    __half* y0    = (__half*)(ws + o); o = align(o + (size_t)NOUT0 * Bsz * 2);
    __half* y1    = (__half*)(ws + o); o = align(o + (size_t)NOUT1 * Bsz * 2);
    __half* y2    = (__half*)(ws + o); o = align(o + (size_t)NOUT2 * Bsz * 2);
    int* cnt      = (int*)(ws + o);    o = align(o + (size_t)CNT_N * 4);
    int* offs     = (int*)(ws + o);    o = align(o + (size_t)OFFS_N * 4);
    int* cursor   = (int*)(ws + o);    o = align(o + (size_t)CNT_N * 4);
    int* csr      = (int*)(ws + o);    o = align(o + (size_t)CSR_N * 4);

    Params P{data, p0, p1, p2, W, bias, src0, dst0, src1, dst1, src2, dst2,
             dataT, y0, y1, y2, cnt, offs, cursor, csr, (float*)d_out};

    int nbpm = 0;
    hipError_t oerr = hipOccupancyMaxActiveBlocksPerMultiprocessor(&nbpm, gnn_all, 256, 0);
    int grid = (oerr == hipSuccess && nbpm > 0) ? nbpm * 256 : 0;  // 256 CUs on MI355X
    if (grid > 1024) grid = 1024;

    hipError_t lerr = hipErrorUnknown;
    if (grid >= 8) {
        void* kargs[] = { &P };
        lerr = hipLaunchCooperativeKernel((void*)gnn_all, dim3(grid), dim3(256),
                                          kargs, 0, stream);
    }
    if (lerr != hipSuccess) {
        // Fallback: proven round-7 split pipeline.
        hipMemsetAsync(cnt, 0, (size_t)CNT_N * 4, stream);
        count_edges<<<(CSR_N + 255) / 256, 256, 0, stream>>>(dst0, dst1, dst2, cnt);
        scan_offs<<<3, 1024, 0, stream>>>(cnt, offs, cursor);
        scatter_edges<<<(CSR_N + 255) / 256, 256, 0, stream>>>(
            src0, dst0, src1, dst1, src2, dst2, cursor, csr);
        transpose_scale<<<dim3((F0 + 63) / 64, Bsz / 64), 256, 0, stream>>>(data, p0, dataT);
        layer_fwd<<<NOUT0, 256, 0, stream>>>(dataT, csr, offs, p1, y0);
        layer_fwd<<<NOUT1, 256, 0, stream>>>(y0, csr + NE0, offs + NOUT0 + 1, p2, y1);
        layer_fwd<<<NOUT2, 256, 0, stream>>>(y1, csr + NE0 + NE1, offs + NOUT0 + NOUT1 + 2,
                                             nullptr, y2);
        head_gemm<<<Bsz / 256, 256, 0, stream>>>(y2, W, bias, (float*)d_out);
    }
}

// Round 9
// 703.405 us; speedup vs baseline: 1.3398x; 1.3398x over previous
//
#include <hip/hip_runtime.h>
#include <hip/hip_fp16.h>

// Problem constants (from reference setup_inputs)
constexpr int Bsz   = 1024;     // batch
constexpr int F0    = 20000;    // input features
constexpr int NOUT0 = 5000, NOUT1 = 1000, NOUT2 = 256;
constexpr int NE0   = 100000, NE1 = 50000, NE2 = 10000;
constexpr int CNT_N  = NOUT0 + NOUT1 + NOUT2;   // 6256
constexpr int OFFS_N = CNT_N + 3;               // 6259
constexpr int CSR_N  = NE0 + NE1 + NE2;         // 160000
constexpr int MAXIDX = 512;                      // max edges staged per dst
constexpr int NTILE_F = (F0 + 63) / 64;          // 313
constexpr int NTILE   = NTILE_F * (Bsz / 64);    // 5008 transpose tiles
constexpr int SCB     = (CSR_N + 255) / 256;     // 625 scatter blocks

union H4 { uint2 u; __half2 h[2]; };

// ---------------------------------------------------------------------------
// Dispatch 1: count (LDS atomics) + scan + write offs/cursor. 3 blocks.
// Block L handles layer L. No global memset needed (counters live in LDS).
__global__ __launch_bounds__(1024) void count_scan(
    const int* __restrict__ dst0, const int* __restrict__ dst1,
    const int* __restrict__ dst2, int* __restrict__ offs, int* __restrict__ cursor)
{
    __shared__ int cnt_lds[NOUT0];   // 20000 B (max layer size)
    __shared__ int sc[1024];
    const int L = blockIdx.x;
    const int t = threadIdx.x;
    const int n  = (L == 0) ? NOUT0 : (L == 1) ? NOUT1 : NOUT2;
    const int ne = (L == 0) ? NE0   : (L == 1) ? NE1   : NE2;
    const int* dst = (L == 0) ? dst0 : (L == 1) ? dst1 : dst2;
    const int cb = (L == 0) ? 0 : (L == 1) ? NOUT0 : NOUT0 + NOUT1;
    const int ob = (L == 0) ? 0 : (L == 1) ? NOUT0 + 1 : NOUT0 + NOUT1 + 2;
    int* ofs = offs + ob;
    int* cur = cursor + cb;

    for (int i = t; i < n; i += 1024) cnt_lds[i] = 0;
    __syncthreads();
    for (int e = t; e < ne; e += 1024) atomicAdd(&cnt_lds[dst[e]], 1);
    __syncthreads();

    constexpr int CH = 5;                 // 1024*5 = 5120 >= 5000
    const int base = t * CH;
    int vals[CH];
    int local = 0;
#pragma unroll
    for (int k = 0; k < CH; ++k) {
        const int i = base + k;
        const int v = (i < n) ? cnt_lds[i] : 0;
        vals[k] = v; local += v;
    }
    sc[t] = local;
    __syncthreads();
    for (int d = 1; d < 1024; d <<= 1) {
        const int v = (t >= d) ? sc[t - d] : 0;
        __syncthreads();
        sc[t] += v;
        __syncthreads();
    }
    int excl = sc[t] - local;
#pragma unroll
    for (int k = 0; k < CH; ++k) {
        const int i = base + k;
        if (i < n) { ofs[i] = excl; cur[i] = excl; }
        excl += vals[k];
    }
    if (t == 1023) ofs[n] = sc[1023];
}

// ---------------------------------------------------------------------------
// Dispatch 2: transpose+scale (blocks < NTILE) || edge scatter (the rest).
__global__ __launch_bounds__(256) void transpose_scatter(
    const float* __restrict__ data, const float* __restrict__ p0,
    __half* __restrict__ dataT,
    const int* __restrict__ src0, const int* __restrict__ dst0,
    const int* __restrict__ src1, const int* __restrict__ dst1,
    const int* __restrict__ src2, const int* __restrict__ dst2,
    int* __restrict__ cursor, int* __restrict__ csr)
{
    const int t = threadIdx.x;
    const int bid = blockIdx.x;
    if (bid < NTILE) {
        __shared__ float tile[64][65];
        const int c0 = (bid % NTILE_F) * 64;   // F0 dim
        const int r0 = (bid / NTILE_F) * 64;   // B dim
        const int f4 = t & 15, rr = t >> 4;
        const int col = c0 + f4 * 4;
        if (col < F0) {                        // F0 % 4 == 0: exact guard
#pragma unroll
            for (int p = 0; p < 4; ++p) {
                const int br = rr + p * 16;
                const float4 v = *(const float4*)&data[(size_t)(r0 + br) * F0 + col];
                tile[br][f4 * 4 + 0] = v.x; tile[br][f4 * 4 + 1] = v.y;
                tile[br][f4 * 4 + 2] = v.z; tile[br][f4 * 4 + 3] = v.w;
            }
        }
        __syncthreads();
        const int b4 = t & 15, fr = t >> 4;
#pragma unroll
        for (int p = 0; p < 4; ++p) {
            const int f = c0 + fr + p * 16;
            if (f < F0) {
                const float s = p0[f];
                H4 o;
                o.h[0] = __floats2half2_rn(tile[b4 * 4 + 0][fr + p * 16] * s,
                                           tile[b4 * 4 + 1][fr + p * 16] * s);
                o.h[1] = __floats2half2_rn(tile[b4 * 4 + 2][fr + p * 16] * s,
                                           tile[b4 * 4 + 3][fr + p * 16] * s);
                *(uint2*)&dataT[(size_t)f * Bsz + r0 + b4 * 4] = o.u;
            }
        }
    } else {
        const int i = (bid - NTILE) * 256 + t;
        if (i < NE0) {
            const int pos = atomicAdd(&cursor[dst0[i]], 1);
            csr[pos] = src0[i];
        } else if (i < NE0 + NE1) {
            const int k = i - NE0;
            const int pos = atomicAdd(&cursor[NOUT0 + dst1[k]], 1);
            csr[NE0 + pos] = src1[k];
        } else if (i < CSR_N) {
            const int k = i - NE0 - NE1;
            const int pos = atomicAdd(&cursor[NOUT0 + NOUT1 + dst2[k]], 1);
            csr[NE0 + NE1 + pos] = src2[k];
        }
    }
}

// ---------------------------------------------------------------------------
// Dispatches 3,4: gather layer (fp16 I/O, fp32 acc), block j = dst bucket j.
__global__ __launch_bounds__(256) void layer_fwd(
    const __half* __restrict__ xT, const int* __restrict__ csr,
    const int* __restrict__ offs, const float* __restrict__ pnext,
    __half* __restrict__ yT)
{
    __shared__ int sidx[MAXIDX];
    const int j = blockIdx.x;
    const int t = threadIdx.x;
    const int beg = offs[j], end = offs[j + 1];
    const int n = end - beg;
    const int np = n < MAXIDX ? n : MAXIDX;
    for (int i = t; i < np; i += 256) sidx[i] = csr[beg + i];
    __syncthreads();

    const int c = t * 4;
    float4 a0 = make_float4(0.f, 0.f, 0.f, 0.f);
    float4 a1 = make_float4(0.f, 0.f, 0.f, 0.f);
    int e = 0;
    for (; e + 2 <= np; e += 2) {
        H4 u0, u1;
        u0.u = *(const uint2*)&xT[(size_t)sidx[e + 0] * Bsz + c];
        u1.u = *(const uint2*)&xT[(size_t)sidx[e + 1] * Bsz + c];
        const float2 f00 = __half22float2(u0.h[0]);
        const float2 f01 = __half22float2(u0.h[1]);
        const float2 f10 = __half22float2(u1.h[0]);
        const float2 f11 = __half22float2(u1.h[1]);
        a0.x += f00.x; a0.y += f00.y; a0.z += f01.x; a0.w += f01.y;
        a1.x += f10.x; a1.y += f10.y; a1.z += f11.x; a1.w += f11.y;
    }
    if (e < np) {
        H4 u; u.u = *(const uint2*)&xT[(size_t)sidx[e] * Bsz + c];
        const float2 f0 = __half22float2(u.h[0]);
        const float2 f1 = __half22float2(u.h[1]);
        a0.x += f0.x; a0.y += f0.y; a0.z += f1.x; a0.w += f1.y;
    }
    for (int ee = MAXIDX; ee < n; ++ee) {   // overflow fallback (never in practice)
        H4 u; u.u = *(const uint2*)&xT[(size_t)csr[beg + ee] * Bsz + c];
        const float2 f0 = __half22float2(u.h[0]);
        const float2 f1 = __half22float2(u.h[1]);
        a0.x += f0.x; a0.y += f0.y; a0.z += f1.x; a0.w += f1.y;
    }
    a0.x += a1.x; a0.y += a1.y; a0.z += a1.z; a0.w += a1.w;

    const float inv = 1.0f / fmaxf((float)n, 1.0f);
    const float sc = (pnext ? pnext[j] : 1.0f) * inv;
    H4 o;
    o.h[0] = __floats2half2_rn(fmaxf(a0.x, 0.f) * sc, fmaxf(a0.y, 0.f) * sc);
    o.h[1] = __floats2half2_rn(fmaxf(a0.z, 0.f) * sc, fmaxf(a0.w, 0.f) * sc);
    *(uint2*)&yT[(size_t)j * Bsz + c] = o.u;
}

// ---------------------------------------------------------------------------
// Dispatch 5: l2 + head fused. 8 blocks, each owns 128 batch cols.
// Gather all 256 l2 outputs for the col slice into LDS (y1 is L2-resident),
// then head GEMM directly; y2 never touches global memory.
__global__ __launch_bounds__(256) void l2_head(
    const __half* __restrict__ y1, const int* __restrict__ csr2,
    const int* __restrict__ offs2, const float* __restrict__ W,
    const float* __restrict__ bias, float* __restrict__ out)
{
    __shared__ __half2 y2s[NOUT2][64];   // 64 KB: 256 dsts x 128 cols (half2)
    __shared__ float wsh[10 * 256];      // 10 KB
    __shared__ float bsh[10];

    const int t = threadIdx.x;
    const int c0 = blockIdx.x * 128;     // batch col base (8 blocks x 128)
    const int cp = t & 63;               // col pair index (2 cols per lane)
    const int grp = t >> 6;              // 0..3

    for (int i = t; i < 2560; i += 256) wsh[i] = W[i];
    if (t < 10) bsh[t] = bias[t];

    for (int j = grp; j < NOUT2; j += 4) {
        const int beg = offs2[j], end = offs2[j + 1];
        float ax = 0.f, ay = 0.f;
        for (int e = beg; e < end; ++e) {
            const int s = csr2[e];
            const __half2 v = *(const __half2*)&y1[(size_t)s * Bsz + c0 + cp * 2];
            const float2 f = __half22float2(v);
            ax += f.x; ay += f.y;
        }
        const float inv = 1.0f / fmaxf((float)(end - beg), 1.0f);
        y2s[j][cp] = __floats2half2_rn(fmaxf(ax * inv, 0.f), fmaxf(ay * inv, 0.f));
    }
    __syncthreads();

    for (int o = grp; o < 10; o += 4) {
        float accx = bsh[o], accy = bsh[o];
        const float* wrow = wsh + o * 256;
        for (int k = 0; k < 256; ++k) {
            const float2 f = __half22float2(y2s[k][cp]);
            const float wk = wrow[k];
            accx += f.x * wk; accy += f.y * wk;
        }
        const int b0 = c0 + cp * 2;
        out[(size_t)b0 * 10 + o] = accx;
        out[(size_t)(b0 + 1) * 10 + o] = accy;
    }
}

// ---------------------------------------------------------------------------
extern "C" void kernel_launch(void* const* d_in, const int* in_sizes, int n_in,
                              void* d_out, int out_size, void* d_ws, size_t ws_size,
                              hipStream_t stream)
{
    const float* data = (const float*)d_in[0];
    const float* p0   = (const float*)d_in[1];
    const float* p1   = (const float*)d_in[2];
    const float* p2   = (const float*)d_in[3];
    const float* W    = (const float*)d_in[4];
    const float* bias = (const float*)d_in[5];
    const int* src0 = (const int*)d_in[6];
    const int* dst0 = (const int*)d_in[7];
    const int* src1 = (const int*)d_in[8];
    const int* dst1 = (const int*)d_in[9];
    const int* src2 = (const int*)d_in[10];
    const int* dst2 = (const int*)d_in[11];

    char* ws = (char*)d_ws;
    auto align = [](size_t x) { return (x + 255) & ~size_t(255); };
    size_t o = 0;
    __half* dataT = (__half*)(ws + o); o = align(o + (size_t)F0 * Bsz * 2);
    __half* y0    = (__half*)(ws + o); o = align(o + (size_t)NOUT0 * Bsz * 2);
    __half* y1    = (__half*)(ws + o); o = align(o + (size_t)NOUT1 * Bsz * 2);
    int* offs     = (int*)(ws + o);    o = align(o + (size_t)OFFS_N * 4);
    int* cursor   = (int*)(ws + o);    o = align(o + (size_t)CNT_N * 4);
    int* csr      = (int*)(ws + o);    o = align(o + (size_t)CSR_N * 4);

    count_scan<<<3, 1024, 0, stream>>>(dst0, dst1, dst2, offs, cursor);
    transpose_scatter<<<NTILE + SCB, 256, 0, stream>>>(
        data, p0, dataT, src0, dst0, src1, dst1, src2, dst2, cursor, csr);
    layer_fwd<<<NOUT0, 256, 0, stream>>>(dataT, csr, offs, p1, y0);
    layer_fwd<<<NOUT1, 256, 0, stream>>>(y0, csr + NE0, offs + NOUT0 + 1, p2, y1);
    l2_head<<<8, 256, 0, stream>>>(y1, csr + NE0 + NE1, offs + NOUT0 + NOUT1 + 2,
                                   W, bias, (float*)d_out);
}

// Round 10
// 143.739 us; speedup vs baseline: 6.5565x; 4.8936x over previous
//
#include <hip/hip_runtime.h>
#include <hip/hip_fp16.h>

// Problem constants (from reference setup_inputs)
constexpr int Bsz   = 1024;     // batch
constexpr int F0    = 20000;    // input features
constexpr int NOUT0 = 5000, NOUT1 = 1000, NOUT2 = 256;
constexpr int NE0   = 100000, NE1 = 50000, NE2 = 10000;
constexpr int CNT_N  = NOUT0 + NOUT1 + NOUT2;   // 6256
constexpr int OFFS_N = CNT_N + 3;               // 6259
constexpr int CSR_N  = NE0 + NE1 + NE2;         // 160000
constexpr int MAXIDX = 512;                      // max edges staged per dst
constexpr int NTILE_F = (F0 + 63) / 64;          // 313
constexpr int NTILE   = NTILE_F * (Bsz / 64);    // 5008 transpose tiles
constexpr int SCB     = (CSR_N + 255) / 256;     // 625 scatter blocks

union H4 { uint2 u; __half2 h[2]; };

// ---------------------------------------------------------------------------
// Dispatch 1: count (LDS atomics) + scan + write offs/cursor. 3 blocks.
__global__ __launch_bounds__(1024) void count_scan(
    const int* __restrict__ dst0, const int* __restrict__ dst1,
    const int* __restrict__ dst2, int* __restrict__ offs, int* __restrict__ cursor)
{
    __shared__ int cnt_lds[NOUT0];   // 20000 B (max layer size)
    __shared__ int sc[1024];
    const int L = blockIdx.x;
    const int t = threadIdx.x;
    const int n  = (L == 0) ? NOUT0 : (L == 1) ? NOUT1 : NOUT2;
    const int ne = (L == 0) ? NE0   : (L == 1) ? NE1   : NE2;
    const int* dst = (L == 0) ? dst0 : (L == 1) ? dst1 : dst2;
    const int cb = (L == 0) ? 0 : (L == 1) ? NOUT0 : NOUT0 + NOUT1;
    const int ob = (L == 0) ? 0 : (L == 1) ? NOUT0 + 1 : NOUT0 + NOUT1 + 2;
    int* ofs = offs + ob;
    int* cur = cursor + cb;

    for (int i = t; i < n; i += 1024) cnt_lds[i] = 0;
    __syncthreads();
    for (int e = t; e < ne; e += 1024) atomicAdd(&cnt_lds[dst[e]], 1);
    __syncthreads();

    constexpr int CH = 5;                 // 1024*5 = 5120 >= 5000
    const int base = t * CH;
    int vals[CH];
    int local = 0;
#pragma unroll
    for (int k = 0; k < CH; ++k) {
        const int i = base + k;
        const int v = (i < n) ? cnt_lds[i] : 0;
        vals[k] = v; local += v;
    }
    sc[t] = local;
    __syncthreads();
    for (int d = 1; d < 1024; d <<= 1) {
        const int v = (t >= d) ? sc[t - d] : 0;
        __syncthreads();
        sc[t] += v;
        __syncthreads();
    }
    int excl = sc[t] - local;
#pragma unroll
    for (int k = 0; k < CH; ++k) {
        const int i = base + k;
        if (i < n) { ofs[i] = excl; cur[i] = excl; }
        excl += vals[k];
    }
    if (t == 1023) ofs[n] = sc[1023];
}

// ---------------------------------------------------------------------------
// Dispatch 2: transpose+scale (blocks < NTILE) || edge scatter (the rest).
__global__ __launch_bounds__(256) void transpose_scatter(
    const float* __restrict__ data, const float* __restrict__ p0,
    __half* __restrict__ dataT,
    const int* __restrict__ src0, const int* __restrict__ dst0,
    const int* __restrict__ src1, const int* __restrict__ dst1,
    const int* __restrict__ src2, const int* __restrict__ dst2,
    int* __restrict__ cursor, int* __restrict__ csr)
{
    const int t = threadIdx.x;
    const int bid = blockIdx.x;
    if (bid < NTILE) {
        __shared__ float tile[64][65];
        const int c0 = (bid % NTILE_F) * 64;   // F0 dim
        const int r0 = (bid / NTILE_F) * 64;   // B dim
        const int f4 = t & 15, rr = t >> 4;
        const int col = c0 + f4 * 4;
        if (col < F0) {                        // F0 % 4 == 0: exact guard
#pragma unroll
            for (int p = 0; p < 4; ++p) {
                const int br = rr + p * 16;
                const float4 v = *(const float4*)&data[(size_t)(r0 + br) * F0 + col];
                tile[br][f4 * 4 + 0] = v.x; tile[br][f4 * 4 + 1] = v.y;
                tile[br][f4 * 4 + 2] = v.z; tile[br][f4 * 4 + 3] = v.w;
            }
        }
        __syncthreads();
        const int b4 = t & 15, fr = t >> 4;
#pragma unroll
        for (int p = 0; p < 4; ++p) {
            const int f = c0 + fr + p * 16;
            if (f < F0) {
                const float s = p0[f];
                H4 o;
                o.h[0] = __floats2half2_rn(tile[b4 * 4 + 0][fr + p * 16] * s,
                                           tile[b4 * 4 + 1][fr + p * 16] * s);
                o.h[1] = __floats2half2_rn(tile[b4 * 4 + 2][fr + p * 16] * s,
                                           tile[b4 * 4 + 3][fr + p * 16] * s);
                *(uint2*)&dataT[(size_t)f * Bsz + r0 + b4 * 4] = o.u;
            }
        }
    } else {
        const int i = (bid - NTILE) * 256 + t;
        if (i < NE0) {
            const int pos = atomicAdd(&cursor[dst0[i]], 1);
            csr[pos] = src0[i];
        } else if (i < NE0 + NE1) {
            const int k = i - NE0;
            const int pos = atomicAdd(&cursor[NOUT0 + dst1[k]], 1);
            csr[NE0 + pos] = src1[k];
        } else if (i < CSR_N) {
            const int k = i - NE0 - NE1;
            const int pos = atomicAdd(&cursor[NOUT0 + NOUT1 + dst2[k]], 1);
            csr[NE0 + NE1 + pos] = src2[k];
        }
    }
}

// ---------------------------------------------------------------------------
// Dispatches 3,4,5: gather layer (fp16 I/O, fp32 acc), block j = dst bucket j.
__global__ __launch_bounds__(256) void layer_fwd(
    const __half* __restrict__ xT, const int* __restrict__ csr,
    const int* __restrict__ offs, const float* __restrict__ pnext,
    __half* __restrict__ yT)
{
    __shared__ int sidx[MAXIDX];
    const int j = blockIdx.x;
    const int t = threadIdx.x;
    const int beg = offs[j], end = offs[j + 1];
    const int n = end - beg;
    const int np = n < MAXIDX ? n : MAXIDX;
    for (int i = t; i < np; i += 256) sidx[i] = csr[beg + i];
    __syncthreads();

    const int c = t * 4;
    float4 a0 = make_float4(0.f, 0.f, 0.f, 0.f);
    float4 a1 = make_float4(0.f, 0.f, 0.f, 0.f);
    int e = 0;
    for (; e + 2 <= np; e += 2) {
        H4 u0, u1;
        u0.u = *(const uint2*)&xT[(size_t)sidx[e + 0] * Bsz + c];
        u1.u = *(const uint2*)&xT[(size_t)sidx[e + 1] * Bsz + c];
        const float2 f00 = __half22float2(u0.h[0]);
        const float2 f01 = __half22float2(u0.h[1]);
        const float2 f10 = __half22float2(u1.h[0]);
        const float2 f11 = __half22float2(u1.h[1]);
        a0.x += f00.x; a0.y += f00.y; a0.z += f01.x; a0.w += f01.y;
        a1.x += f10.x; a1.y += f10.y; a1.z += f11.x; a1.w += f11.y;
    }
    if (e < np) {
        H4 u; u.u = *(const uint2*)&xT[(size_t)sidx[e] * Bsz + c];
        const float2 f0 = __half22float2(u.h[0]);
        const float2 f1 = __half22float2(u.h[1]);
        a0.x += f0.x; a0.y += f0.y; a0.z += f1.x; a0.w += f1.y;
    }
    for (int ee = MAXIDX; ee < n; ++ee) {   // overflow fallback (never in practice)
        H4 u; u.u = *(const uint2*)&xT[(size_t)csr[beg + ee] * Bsz + c];
        const float2 f0 = __half22float2(u.h[0]);
        const float2 f1 = __half22float2(u.h[1]);
        a0.x += f0.x; a0.y += f0.y; a0.z += f1.x; a0.w += f1.y;
    }
    a0.x += a1.x; a0.y += a1.y; a0.z += a1.z; a0.w += a1.w;

    const float inv = 1.0f / fmaxf((float)n, 1.0f);
    const float sc = (pnext ? pnext[j] : 1.0f) * inv;
    H4 o;
    o.h[0] = __floats2half2_rn(fmaxf(a0.x, 0.f) * sc, fmaxf(a0.y, 0.f) * sc);
    o.h[1] = __floats2half2_rn(fmaxf(a0.z, 0.f) * sc, fmaxf(a0.w, 0.f) * sc);
    *(uint2*)&yT[(size_t)j * Bsz + c] = o.u;
}

// ---------------------------------------------------------------------------
// Dispatch 6: head GEMM. out (B,10) = y2 (B,256) @ W.T + b, y2 transposed fp16.
__global__ __launch_bounds__(256) void head_gemm(
    const __half* __restrict__ y2T, const float* __restrict__ W,
    const float* __restrict__ bias, float* __restrict__ out)
{
    __shared__ float ws[10 * 256];
    __shared__ float bs[10];
    const int t = threadIdx.x;
    for (int i = t; i < 10 * 256; i += 256) ws[i] = W[i];
    if (t < 10) bs[t] = bias[t];
    __syncthreads();

    const int b = blockIdx.x * 256 + t;
    float acc[10];
#pragma unroll
    for (int o = 0; o < 10; ++o) acc[o] = bs[o];
    for (int k = 0; k < 256; ++k) {
        const float v = __half2float(y2T[(size_t)k * Bsz + b]);
#pragma unroll
        for (int o = 0; o < 10; ++o) acc[o] += v * ws[o * 256 + k];
    }
#pragma unroll
    for (int o = 0; o < 10; ++o) out[(size_t)b * 10 + o] = acc[o];
}

// ---------------------------------------------------------------------------
extern "C" void kernel_launch(void* const* d_in, const int* in_sizes, int n_in,
                              void* d_out, int out_size, void* d_ws, size_t ws_size,
                              hipStream_t stream)
{
    const float* data = (const float*)d_in[0];
    const float* p0   = (const float*)d_in[1];
    const float* p1   = (const float*)d_in[2];
    const float* p2   = (const float*)d_in[3];
    const float* W    = (const float*)d_in[4];
    const float* bias = (const float*)d_in[5];
    const int* src0 = (const int*)d_in[6];
    const int* dst0 = (const int*)d_in[7];
    const int* src1 = (const int*)d_in[8];
    const int* dst1 = (const int*)d_in[9];
    const int* src2 = (const int*)d_in[10];
    const int* dst2 = (const int*)d_in[11];

    char* ws = (char*)d_ws;
    auto align = [](size_t x) { return (x + 255) & ~size_t(255); };
    size_t o = 0;
    __half* dataT = (__half*)(ws + o); o = align(o + (size_t)F0 * Bsz * 2);
    __half* y0    = (__half*)(ws + o); o = align(o + (size_t)NOUT0 * Bsz * 2);
    __half* y1    = (__half*)(ws + o); o = align(o + (size_t)NOUT1 * Bsz * 2);
    __half* y2    = (__half*)(ws + o); o = align(o + (size_t)NOUT2 * Bsz * 2);
    int* offs     = (int*)(ws + o);    o = align(o + (size_t)OFFS_N * 4);
    int* cursor   = (int*)(ws + o);    o = align(o + (size_t)CNT_N * 4);
    int* csr      = (int*)(ws + o);    o = align(o + (size_t)CSR_N * 4);

    count_scan<<<3, 1024, 0, stream>>>(dst0, dst1, dst2, offs, cursor);
    transpose_scatter<<<NTILE + SCB, 256, 0, stream>>>(
        data, p0, dataT, src0, dst0, src1, dst1, src2, dst2, cursor, csr);
    layer_fwd<<<NOUT0, 256, 0, stream>>>(dataT, csr, offs, p1, y0);
    layer_fwd<<<NOUT1, 256, 0, stream>>>(y0, csr + NE0, offs + NOUT0 + 1, p2, y1);
    layer_fwd<<<NOUT2, 256, 0, stream>>>(y1, csr + NE0 + NE1, offs + NOUT0 + NOUT1 + 2,
                                         nullptr, y2);
    head_gemm<<<Bsz / 256, 256, 0, stream>>>(y2, W, bias, (float*)d_out);
}

// Round 11
// 124.983 us; speedup vs baseline: 7.5405x; 1.1501x over previous
//
#include <hip/hip_runtime.h>
#include <hip/hip_fp16.h>

// Problem constants (from reference setup_inputs)
constexpr int Bsz   = 1024;     // batch
constexpr int F0    = 20000;    // input features
constexpr int NOUT0 = 5000, NOUT1 = 1000, NOUT2 = 256;
constexpr int NE0   = 100000, NE1 = 50000, NE2 = 10000;
constexpr int CNT_N  = NOUT0 + NOUT1 + NOUT2;   // 6256
constexpr int OFFS_N = CNT_N + 3;               // 6259
constexpr int CSR_N  = NE0 + NE1 + NE2;         // 160000
constexpr int MAXIDX = 512;                      // max edges staged per dst
constexpr int NTILE_F = (F0 + 63) / 64;          // 313
constexpr int NTILE   = NTILE_F * (Bsz / 64);    // 5008 transpose tiles
constexpr int SCB     = (CSR_N + 255) / 256;     // 625 scatter blocks
constexpr int NSLICE  = 8;                       // column slices == XCD count
constexpr int SLW     = Bsz / NSLICE;            // 128 cols per slice

union H4 { uint2 u; __half2 h[2]; };

// ---------------------------------------------------------------------------
// Dispatch 1: count (LDS atomics) + scan + write offs/cursor. 3 blocks.
__global__ __launch_bounds__(1024) void count_scan(
    const int* __restrict__ dst0, const int* __restrict__ dst1,
    const int* __restrict__ dst2, int* __restrict__ offs, int* __restrict__ cursor)
{
    __shared__ int cnt_lds[NOUT0];   // 20000 B (max layer size)
    __shared__ int sc[1024];
    const int L = blockIdx.x;
    const int t = threadIdx.x;
    const int n  = (L == 0) ? NOUT0 : (L == 1) ? NOUT1 : NOUT2;
    const int ne = (L == 0) ? NE0   : (L == 1) ? NE1   : NE2;
    const int* dst = (L == 0) ? dst0 : (L == 1) ? dst1 : dst2;
    const int cb = (L == 0) ? 0 : (L == 1) ? NOUT0 : NOUT0 + NOUT1;
    const int ob = (L == 0) ? 0 : (L == 1) ? NOUT0 + 1 : NOUT0 + NOUT1 + 2;
    int* ofs = offs + ob;
    int* cur = cursor + cb;

    for (int i = t; i < n; i += 1024) cnt_lds[i] = 0;
    __syncthreads();
    for (int e = t; e < ne; e += 1024) atomicAdd(&cnt_lds[dst[e]], 1);
    __syncthreads();

    constexpr int CH = 5;                 // 1024*5 = 5120 >= 5000
    const int base = t * CH;
    int vals[CH];
    int local = 0;
#pragma unroll
    for (int k = 0; k < CH; ++k) {
        const int i = base + k;
        const int v = (i < n) ? cnt_lds[i] : 0;
        vals[k] = v; local += v;
    }
    sc[t] = local;
    __syncthreads();
    for (int d = 1; d < 1024; d <<= 1) {
        const int v = (t >= d) ? sc[t - d] : 0;
        __syncthreads();
        sc[t] += v;
        __syncthreads();
    }
    int excl = sc[t] - local;
#pragma unroll
    for (int k = 0; k < CH; ++k) {
        const int i = base + k;
        if (i < n) { ofs[i] = excl; cur[i] = excl; }
        excl += vals[k];
    }
    if (t == 1023) ofs[n] = sc[1023];
}

// ---------------------------------------------------------------------------
// Dispatch 2: transpose+scale (blocks < NTILE) || edge scatter (the rest).
__global__ __launch_bounds__(256) void transpose_scatter(
    const float* __restrict__ data, const float* __restrict__ p0,
    __half* __restrict__ dataT,
    const int* __restrict__ src0, const int* __restrict__ dst0,
    const int* __restrict__ src1, const int* __restrict__ dst1,
    const int* __restrict__ src2, const int* __restrict__ dst2,
    int* __restrict__ cursor, int* __restrict__ csr)
{
    const int t = threadIdx.x;
    const int bid = blockIdx.x;
    if (bid < NTILE) {
        __shared__ float tile[64][65];
        const int c0 = (bid % NTILE_F) * 64;   // F0 dim
        const int r0 = (bid / NTILE_F) * 64;   // B dim
        const int f4 = t & 15, rr = t >> 4;
        const int col = c0 + f4 * 4;
        if (col < F0) {                        // F0 % 4 == 0: exact guard
#pragma unroll
            for (int p = 0; p < 4; ++p) {
                const int br = rr + p * 16;
                const float4 v = *(const float4*)&data[(size_t)(r0 + br) * F0 + col];
                tile[br][f4 * 4 + 0] = v.x; tile[br][f4 * 4 + 1] = v.y;
                tile[br][f4 * 4 + 2] = v.z; tile[br][f4 * 4 + 3] = v.w;
            }
        }
        __syncthreads();
        const int b4 = t & 15, fr = t >> 4;
#pragma unroll
        for (int p = 0; p < 4; ++p) {
            const int f = c0 + fr + p * 16;
            if (f < F0) {
                const float s = p0[f];
                H4 o;
                o.h[0] = __floats2half2_rn(tile[b4 * 4 + 0][fr + p * 16] * s,
                                           tile[b4 * 4 + 1][fr + p * 16] * s);
                o.h[1] = __floats2half2_rn(tile[b4 * 4 + 2][fr + p * 16] * s,
                                           tile[b4 * 4 + 3][fr + p * 16] * s);
                *(uint2*)&dataT[(size_t)f * Bsz + r0 + b4 * 4] = o.u;
            }
        }
    } else {
        const int i = (bid - NTILE) * 256 + t;
        if (i < NE0) {
            const int pos = atomicAdd(&cursor[dst0[i]], 1);
            csr[pos] = src0[i];
        } else if (i < NE0 + NE1) {
            const int k = i - NE0;
            const int pos = atomicAdd(&cursor[NOUT0 + dst1[k]], 1);
            csr[NE0 + pos] = src1[k];
        } else if (i < CSR_N) {
            const int k = i - NE0 - NE1;
            const int pos = atomicAdd(&cursor[NOUT0 + NOUT1 + dst2[k]], 1);
            csr[NE0 + NE1 + pos] = src2[k];
        }
    }
}

// ---------------------------------------------------------------------------
// Dispatches 3,4,5: XCD-sliced gather layer.
// Block = (dst j, column slice s), slice = bid & 7 -> lands on XCD s via
// round-robin dispatch, so XCD s only ever touches columns [128s,128s+128):
// per-XCD L2 working set = nrows * 256B (l0: 5.1MB, l1: 1.25MB, l2: 0.25MB).
// One wave per block; thread t owns cols [slice*128 + 2t, +2) as half2.
// 4-edge unroll keeps 4 loads in flight (latency cover at ~16 blocks/CU).
template<int LAYER>
__global__ __launch_bounds__(64) void layer_slice(
    const __half* __restrict__ xT, const int* __restrict__ csr,
    const int* __restrict__ offs, const float* __restrict__ pnext,
    __half* __restrict__ yT)
{
    __shared__ int sidx[MAXIDX];
    const int bid = blockIdx.x;
    const int slice = bid & (NSLICE - 1);
    const int j = bid >> 3;
    const int t = threadIdx.x;
    const int beg = offs[j], end = offs[j + 1];
    const int n = end - beg;
    const int np = n < MAXIDX ? n : MAXIDX;
    for (int i = t; i < np; i += 64) sidx[i] = csr[beg + i];
    __syncthreads();

    const int c = slice * SLW + t * 2;
    float a0x = 0.f, a0y = 0.f, a1x = 0.f, a1y = 0.f;
    float a2x = 0.f, a2y = 0.f, a3x = 0.f, a3y = 0.f;
    int e = 0;
    for (; e + 4 <= np; e += 4) {
        const __half2 v0 = *(const __half2*)&xT[(size_t)sidx[e + 0] * Bsz + c];
        const __half2 v1 = *(const __half2*)&xT[(size_t)sidx[e + 1] * Bsz + c];
        const __half2 v2 = *(const __half2*)&xT[(size_t)sidx[e + 2] * Bsz + c];
        const __half2 v3 = *(const __half2*)&xT[(size_t)sidx[e + 3] * Bsz + c];
        const float2 f0 = __half22float2(v0);
        const float2 f1 = __half22float2(v1);
        const float2 f2 = __half22float2(v2);
        const float2 f3 = __half22float2(v3);
        a0x += f0.x; a0y += f0.y; a1x += f1.x; a1y += f1.y;
        a2x += f2.x; a2y += f2.y; a3x += f3.x; a3y += f3.y;
    }
    for (; e < np; ++e) {
        const float2 f = __half22float2(*(const __half2*)&xT[(size_t)sidx[e] * Bsz + c]);
        a0x += f.x; a0y += f.y;
    }
    for (int ee = MAXIDX; ee < n; ++ee) {   // overflow fallback (never in practice)
        const float2 f = __half22float2(*(const __half2*)&xT[(size_t)csr[beg + ee] * Bsz + c]);
        a0x += f.x; a0y += f.y;
    }
    const float ax = a0x + a1x + a2x + a3x;
    const float ay = a0y + a1y + a2y + a3y;

    const float inv = 1.0f / fmaxf((float)n, 1.0f);
    const float sc = (pnext ? pnext[j] : 1.0f) * inv;
    const __half2 o = __floats2half2_rn(fmaxf(ax, 0.f) * sc, fmaxf(ay, 0.f) * sc);
    *(__half2*)&yT[(size_t)j * Bsz + c] = o;
}

// ---------------------------------------------------------------------------
// Dispatch 6: head GEMM. out (B,10) = y2 (B,256) @ W.T + b, y2 transposed fp16.
__global__ __launch_bounds__(256) void head_gemm(
    const __half* __restrict__ y2T, const float* __restrict__ W,
    const float* __restrict__ bias, float* __restrict__ out)
{
    __shared__ float ws[10 * 256];
    __shared__ float bs[10];
    const int t = threadIdx.x;
    for (int i = t; i < 10 * 256; i += 256) ws[i] = W[i];
    if (t < 10) bs[t] = bias[t];
    __syncthreads();

    const int b = blockIdx.x * 256 + t;
    float acc[10];
#pragma unroll
    for (int o = 0; o < 10; ++o) acc[o] = bs[o];
    for (int k = 0; k < 256; ++k) {
        const float v = __half2float(y2T[(size_t)k * Bsz + b]);
#pragma unroll
        for (int o = 0; o < 10; ++o) acc[o] += v * ws[o * 256 + k];
    }
#pragma unroll
    for (int o = 0; o < 10; ++o) out[(size_t)b * 10 + o] = acc[o];
}

// ---------------------------------------------------------------------------
extern "C" void kernel_launch(void* const* d_in, const int* in_sizes, int n_in,
                              void* d_out, int out_size, void* d_ws, size_t ws_size,
                              hipStream_t stream)
{
    const float* data = (const float*)d_in[0];
    const float* p0   = (const float*)d_in[1];
    const float* p1   = (const float*)d_in[2];
    const float* p2   = (const float*)d_in[3];
    const float* W    = (const float*)d_in[4];
    const float* bias = (const float*)d_in[5];
    const int* src0 = (const int*)d_in[6];
    const int* dst0 = (const int*)d_in[7];
    const int* src1 = (const int*)d_in[8];
    const int* dst1 = (const int*)d_in[9];
    const int* src2 = (const int*)d_in[10];
    const int* dst2 = (const int*)d_in[11];

    char* ws = (char*)d_ws;
    auto align = [](size_t x) { return (x + 255) & ~size_t(255); };
    size_t o = 0;
    __half* dataT = (__half*)(ws + o); o = align(o + (size_t)F0 * Bsz * 2);
    __half* y0    = (__half*)(ws + o); o = align(o + (size_t)NOUT0 * Bsz * 2);
    __half* y1    = (__half*)(ws + o); o = align(o + (size_t)NOUT1 * Bsz * 2);
    __half* y2    = (__half*)(ws + o); o = align(o + (size_t)NOUT2 * Bsz * 2);
    int* offs     = (int*)(ws + o);    o = align(o + (size_t)OFFS_N * 4);
    int* cursor   = (int*)(ws + o);    o = align(o + (size_t)CNT_N * 4);
    int* csr      = (int*)(ws + o);    o = align(o + (size_t)CSR_N * 4);

    count_scan<<<3, 1024, 0, stream>>>(dst0, dst1, dst2, offs, cursor);
    transpose_scatter<<<NTILE + SCB, 256, 0, stream>>>(
        data, p0, dataT, src0, dst0, src1, dst1, src2, dst2, cursor, csr);
    layer_slice<0><<<NOUT0 * NSLICE, 64, 0, stream>>>(dataT, csr, offs, p1, y0);
    layer_slice<1><<<NOUT1 * NSLICE, 64, 0, stream>>>(y0, csr + NE0, offs + NOUT0 + 1, p2, y1);
    layer_slice<2><<<NOUT2 * NSLICE, 64, 0, stream>>>(y1, csr + NE0 + NE1,
                                                      offs + NOUT0 + NOUT1 + 2, nullptr, y2);
    head_gemm<<<Bsz / 256, 256, 0, stream>>>(y2, W, bias, (float*)d_out);
}

// Round 12
// 117.676 us; speedup vs baseline: 8.0087x; 1.0621x over previous
//
#include <hip/hip_runtime.h>
#include <hip/hip_fp16.h>

// Problem constants (from reference setup_inputs)
constexpr int Bsz   = 1024;     // batch
constexpr int F0    = 20000;    // input features
constexpr int NOUT0 = 5000, NOUT1 = 1000, NOUT2 = 256;
constexpr int NE0   = 100000, NE1 = 50000, NE2 = 10000;
constexpr int CNT_N  = NOUT0 + NOUT1 + NOUT2;   // 6256
constexpr int OFFS_N = CNT_N + 3;               // 6259
constexpr int CSR_N  = NE0 + NE1 + NE2;         // 160000
constexpr int MAXIDX = 512;                      // max edges staged per dst
constexpr int NTILE_F = (F0 + 63) / 64;          // 313
constexpr int NTILE   = NTILE_F * (Bsz / 64);    // 5008 transpose tiles
constexpr int SCB     = (CSR_N + 255) / 256;     // 625 scatter blocks
constexpr int NSLICE  = 8;                       // column slices == XCD count
constexpr int SLW     = Bsz / NSLICE;            // 128 cols per slice

union H4 { uint2 u; __half2 h[2]; };

// ---------------------------------------------------------------------------
// Dispatch 2: count dst in-degrees (wide, global atomics — ~3µs measured).
__global__ __launch_bounds__(256) void count_edges(
    const int* __restrict__ dst0, const int* __restrict__ dst1,
    const int* __restrict__ dst2, int* __restrict__ cnt)
{
    const int i = blockIdx.x * 256 + threadIdx.x;
    if (i < NE0)                 atomicAdd(&cnt[dst0[i]], 1);
    else if (i < NE0 + NE1)      atomicAdd(&cnt[NOUT0 + dst1[i - NE0]], 1);
    else if (i < CSR_N)          atomicAdd(&cnt[NOUT0 + NOUT1 + dst2[i - NE0 - NE1]], 1);
}

// ---------------------------------------------------------------------------
// Dispatch 3: scan counts -> offs + cursor. 3 blocks (one per layer).
__global__ __launch_bounds__(1024) void scan_offs(
    const int* __restrict__ cnt, int* __restrict__ offs, int* __restrict__ cursor)
{
    const int L = blockIdx.x;
    const int t = threadIdx.x;
    const int n  = (L == 0) ? NOUT0 : (L == 1) ? NOUT1 : NOUT2;
    const int cb = (L == 0) ? 0 : (L == 1) ? NOUT0 : NOUT0 + NOUT1;
    const int ob = (L == 0) ? 0 : (L == 1) ? NOUT0 + 1 : NOUT0 + NOUT1 + 2;
    const int* c = cnt + cb;
    int* ofs = offs + ob;
    int* cur = cursor + cb;

    __shared__ int sc[1024];
    constexpr int CH = 5;                 // 1024*5 = 5120 >= 5000
    const int base = t * CH;
    int vals[CH];
    int local = 0;
#pragma unroll
    for (int k = 0; k < CH; ++k) {
        const int i = base + k;
        const int v = (i < n) ? c[i] : 0;
        vals[k] = v; local += v;
    }
    sc[t] = local;
    __syncthreads();
    for (int d = 1; d < 1024; d <<= 1) {
        const int v = (t >= d) ? sc[t - d] : 0;
        __syncthreads();
        sc[t] += v;
        __syncthreads();
    }
    int excl = sc[t] - local;
#pragma unroll
    for (int k = 0; k < CH; ++k) {
        const int i = base + k;
        if (i < n) { ofs[i] = excl; cur[i] = excl; }
        excl += vals[k];
    }
    if (t == 1023) ofs[n] = sc[1023];
}

// ---------------------------------------------------------------------------
// Dispatch 4: transpose+scale (blocks < NTILE) || edge scatter (the rest).
__global__ __launch_bounds__(256) void transpose_scatter(
    const float* __restrict__ data, const float* __restrict__ p0,
    __half* __restrict__ dataT,
    const int* __restrict__ src0, const int* __restrict__ dst0,
    const int* __restrict__ src1, const int* __restrict__ dst1,
    const int* __restrict__ src2, const int* __restrict__ dst2,
    int* __restrict__ cursor, int* __restrict__ csr)
{
    const int t = threadIdx.x;
    const int bid = blockIdx.x;
    if (bid < NTILE) {
        __shared__ float tile[64][65];
        const int c0 = (bid % NTILE_F) * 64;   // F0 dim
        const int r0 = (bid / NTILE_F) * 64;   // B dim
        const int f4 = t & 15, rr = t >> 4;
        const int col = c0 + f4 * 4;
        if (col < F0) {                        // F0 % 4 == 0: exact guard
#pragma unroll
            for (int p = 0; p < 4; ++p) {
                const int br = rr + p * 16;
                const float4 v = *(const float4*)&data[(size_t)(r0 + br) * F0 + col];
                tile[br][f4 * 4 + 0] = v.x; tile[br][f4 * 4 + 1] = v.y;
                tile[br][f4 * 4 + 2] = v.z; tile[br][f4 * 4 + 3] = v.w;
            }
        }
        __syncthreads();
        const int b4 = t & 15, fr = t >> 4;
#pragma unroll
        for (int p = 0; p < 4; ++p) {
            const int f = c0 + fr + p * 16;
            if (f < F0) {
                const float s = p0[f];
                H4 o;
                o.h[0] = __floats2half2_rn(tile[b4 * 4 + 0][fr + p * 16] * s,
                                           tile[b4 * 4 + 1][fr + p * 16] * s);
                o.h[1] = __floats2half2_rn(tile[b4 * 4 + 2][fr + p * 16] * s,
                                           tile[b4 * 4 + 3][fr + p * 16] * s);
                *(uint2*)&dataT[(size_t)f * Bsz + r0 + b4 * 4] = o.u;
            }
        }
    } else {
        const int i = (bid - NTILE) * 256 + t;
        if (i < NE0) {
            const int pos = atomicAdd(&cursor[dst0[i]], 1);
            csr[pos] = src0[i];
        } else if (i < NE0 + NE1) {
            const int k = i - NE0;
            const int pos = atomicAdd(&cursor[NOUT0 + dst1[k]], 1);
            csr[NE0 + pos] = src1[k];
        } else if (i < CSR_N) {
            const int k = i - NE0 - NE1;
            const int pos = atomicAdd(&cursor[NOUT0 + NOUT1 + dst2[k]], 1);
            csr[NE0 + NE1 + pos] = src2[k];
        }
    }
}

// ---------------------------------------------------------------------------
// Dispatches 5,6,7: XCD-sliced gather layer.
// Block = (dst j, column slice s), slice = bid & 7 -> XCD s via round-robin;
// per-XCD L2 working set = nrows * 256B (l0: 5.1MB, l1: 1.25MB, l2: 0.25MB).
// One wave per block; thread t owns cols [slice*128 + 2t, +2) as half2.
template<int LAYER>
__global__ __launch_bounds__(64) void layer_slice(
    const __half* __restrict__ xT, const int* __restrict__ csr,
    const int* __restrict__ offs, const float* __restrict__ pnext,
    __half* __restrict__ yT)
{
    __shared__ int sidx[MAXIDX];
    const int bid = blockIdx.x;
    const int slice = bid & (NSLICE - 1);
    const int j = bid >> 3;
    const int t = threadIdx.x;
    const int beg = offs[j], end = offs[j + 1];
    const int n = end - beg;
    const int np = n < MAXIDX ? n : MAXIDX;
    for (int i = t; i < np; i += 64) sidx[i] = csr[beg + i];
    __syncthreads();

    const int c = slice * SLW + t * 2;
    float a0x = 0.f, a0y = 0.f, a1x = 0.f, a1y = 0.f;
    float a2x = 0.f, a2y = 0.f, a3x = 0.f, a3y = 0.f;
    int e = 0;
    for (; e + 4 <= np; e += 4) {
        const __half2 v0 = *(const __half2*)&xT[(size_t)sidx[e + 0] * Bsz + c];
        const __half2 v1 = *(const __half2*)&xT[(size_t)sidx[e + 1] * Bsz + c];
        const __half2 v2 = *(const __half2*)&xT[(size_t)sidx[e + 2] * Bsz + c];
        const __half2 v3 = *(const __half2*)&xT[(size_t)sidx[e + 3] * Bsz + c];
        const float2 f0 = __half22float2(v0);
        const float2 f1 = __half22float2(v1);
        const float2 f2 = __half22float2(v2);
        const float2 f3 = __half22float2(v3);
        a0x += f0.x; a0y += f0.y; a1x += f1.x; a1y += f1.y;
        a2x += f2.x; a2y += f2.y; a3x += f3.x; a3y += f3.y;
    }
    for (; e < np; ++e) {
        const float2 f = __half22float2(*(const __half2*)&xT[(size_t)sidx[e] * Bsz + c]);
        a0x += f.x; a0y += f.y;
    }
    for (int ee = MAXIDX; ee < n; ++ee) {   // overflow fallback (never in practice)
        const float2 f = __half22float2(*(const __half2*)&xT[(size_t)csr[beg + ee] * Bsz + c]);
        a0x += f.x; a0y += f.y;
    }
    const float ax = a0x + a1x + a2x + a3x;
    const float ay = a0y + a1y + a2y + a3y;

    const float inv = 1.0f / fmaxf((float)n, 1.0f);
    const float sc = (pnext ? pnext[j] : 1.0f) * inv;
    const __half2 o = __floats2half2_rn(fmaxf(ax, 0.f) * sc, fmaxf(ay, 0.f) * sc);
    *(__half2*)&yT[(size_t)j * Bsz + c] = o;
}

// ---------------------------------------------------------------------------
// Dispatch 8: head GEMM. out (B,10) = y2 (B,256) @ W.T + b, y2 transposed fp16.
__global__ __launch_bounds__(256) void head_gemm(
    const __half* __restrict__ y2T, const float* __restrict__ W,
    const float* __restrict__ bias, float* __restrict__ out)
{
    __shared__ float ws[10 * 256];
    __shared__ float bs[10];
    const int t = threadIdx.x;
    for (int i = t; i < 10 * 256; i += 256) ws[i] = W[i];
    if (t < 10) bs[t] = bias[t];
    __syncthreads();

    const int b = blockIdx.x * 256 + t;
    float acc[10];
#pragma unroll
    for (int o = 0; o < 10; ++o) acc[o] = bs[o];
    for (int k = 0; k < 256; ++k) {
        const float v = __half2float(y2T[(size_t)k * Bsz + b]);
#pragma unroll
        for (int o = 0; o < 10; ++o) acc[o] += v * ws[o * 256 + k];
    }
#pragma unroll
    for (int o = 0; o < 10; ++o) out[(size_t)b * 10 + o] = acc[o];
}

// ---------------------------------------------------------------------------
extern "C" void kernel_launch(void* const* d_in, const int* in_sizes, int n_in,
                              void* d_out, int out_size, void* d_ws, size_t ws_size,
                              hipStream_t stream)
{
    const float* data = (const float*)d_in[0];
    const float* p0   = (const float*)d_in[1];
    const float* p1   = (const float*)d_in[2];
    const float* p2   = (const float*)d_in[3];
    const float* W    = (const float*)d_in[4];
    const float* bias = (const float*)d_in[5];
    const int* src0 = (const int*)d_in[6];
    const int* dst0 = (const int*)d_in[7];
    const int* src1 = (const int*)d_in[8];
    const int* dst1 = (const int*)d_in[9];
    const int* src2 = (const int*)d_in[10];
    const int* dst2 = (const int*)d_in[11];

    char* ws = (char*)d_ws;
    auto align = [](size_t x) { return (x + 255) & ~size_t(255); };
    size_t o = 0;
    __half* dataT = (__half*)(ws + o); o = align(o + (size_t)F0 * Bsz * 2);
    __half* y0    = (__half*)(ws + o); o = align(o + (size_t)NOUT0 * Bsz * 2);
    __half* y1    = (__half*)(ws + o); o = align(o + (size_t)NOUT1 * Bsz * 2);
    __half* y2    = (__half*)(ws + o); o = align(o + (size_t)NOUT2 * Bsz * 2);
    int* cnt      = (int*)(ws + o);    o = align(o + (size_t)CNT_N * 4);
    int* offs     = (int*)(ws + o);    o = align(o + (size_t)OFFS_N * 4);
    int* cursor   = (int*)(ws + o);    o = align(o + (size_t)CNT_N * 4);
    int* csr      = (int*)(ws + o);    o = align(o + (size_t)CSR_N * 4);

    hipMemsetAsync(cnt, 0, (size_t)CNT_N * 4, stream);
    count_edges<<<SCB, 256, 0, stream>>>(dst0, dst1, dst2, cnt);
    scan_offs<<<3, 1024, 0, stream>>>(cnt, offs, cursor);
    transpose_scatter<<<NTILE + SCB, 256, 0, stream>>>(
        data, p0, dataT, src0, dst0, src1, dst1, src2, dst2, cursor, csr);
    layer_slice<0><<<NOUT0 * NSLICE, 64, 0, stream>>>(dataT, csr, offs, p1, y0);
    layer_slice<1><<<NOUT1 * NSLICE, 64, 0, stream>>>(y0, csr + NE0, offs + NOUT0 + 1, p2, y1);
    layer_slice<2><<<NOUT2 * NSLICE, 64, 0, stream>>>(y1, csr + NE0 + NE1,
                                                      offs + NOUT0 + NOUT1 + 2, nullptr, y2);
    head_gemm<<<Bsz / 256, 256, 0, stream>>>(y2, W, bias, (float*)d_out);
}